// Round 15
// baseline (427.390 us; speedup 1.0000x reference)
//
#include <hip/hip_runtime.h>
#include <stdint.h>

// ---------------- problem constants ----------------
#define NP   250000
#define NA   10000
#define NBLK 5
#define NL   20            // 5 blocks x (2 iW + 2 oW) layers
#define BLOB_W_BYTES 16384               // 128x128 fp8 e4m3, row=out-feature, XOR-swizzled
#define BLOB_BYTES   16896               // + 128 fp32 folded biases (512 B)

#define LOG2E 1.4426950408889634f
#define LN2   0.6931471805599453f

typedef float  f32x4  __attribute__((ext_vector_type(4)));
typedef unsigned short ushort_t;
typedef unsigned int   uint_t;
typedef int4  i4_ma __attribute__((may_alias));
typedef uint2 u2_ma __attribute__((may_alias));
typedef uint_t u1_ma __attribute__((may_alias));

// raw single-instruction transcendentals (v_exp_f32 / v_log_f32); args bounded
#if __has_builtin(__builtin_amdgcn_exp2f)
#define FEXP2(x) __builtin_amdgcn_exp2f(x)
#else
#define FEXP2(x) exp2f(x)
#endif
#if __has_builtin(__builtin_amdgcn_logf)
#define FLOG2(x) __builtin_amdgcn_logf(x)
#else
#define FLOG2(x) log2f(x)
#endif

// ---------------- static device scratch ----------------
__device__ uint8_t g_blob[NL * BLOB_BYTES];   // swizzled fp8 weights + folded f32 biases
__device__ float   g_outs[NBLK * NA * 2];     // per-block per-atom segment sums
__device__ float   g_nh[1];
__device__ float   g_Rf[NA * 3];
__device__ float   g_oWfF[NBLK * 128 * 2];    // ln2-prescaled head weights
__device__ float   g_oBfF[NBLK * 2];          // head biases (unmodified)
__device__ float   g_scF[190];
__device__ float   g_shF[190];

static __device__ __forceinline__ float bf2f(ushort_t u) {
    return __uint_as_float(((uint_t)u) << 16);
}
// e4m3fn (OCP) encoder — fallback only
static __device__ uint8_t f2fp8(float f) {
    uint_t u = __float_as_uint(f);
    uint8_t s = (uint8_t)((u >> 24) & 0x80);
    float af = fabsf(f);
    if (af != af) return (uint8_t)(s | 0x7F);
    if (af > 448.0f) return (uint8_t)(s | 0x7E);
    int e = (int)((u >> 23) & 0xFF) - 127;
    uint_t m = u & 0x7FFFFFu;
    if (e >= -6) {
        uint_t mant = m >> 20;
        uint_t rest = m & 0xFFFFFu;
        if (rest > 0x80000u || (rest == 0x80000u && (mant & 1u))) mant++;
        uint_t ee = (uint_t)(e + 7);
        if (mant == 8u) { mant = 0u; ee++; }
        if (ee > 15u || (ee == 15u && mant > 6u)) return (uint8_t)(s | 0x7E);
        return (uint8_t)(s | (ee << 3) | mant);
    }
    int qq = (int)rintf(af * 512.0f);      // subnormal: grid 2^-9
    if (qq > 7) return (uint8_t)(s | 0x08);
    return (uint8_t)(s | (uint_t)qq);
}
// pack 2 f32 -> 2 fp8 bytes into low/high half of a dword (HI = immediate)
template <bool HI>
static __device__ __forceinline__ int cvtpk2(float a, float b, int old) {
#if __has_builtin(__builtin_amdgcn_cvt_pk_fp8_f32)
    return __builtin_amdgcn_cvt_pk_fp8_f32(a, b, old, HI);
#else
    int p = (int)f2fp8(a) | ((int)f2fp8(b) << 8);
    return HI ? (int)((old & 0x0000FFFF) | ((uint_t)p << 16))
              : (int)((old & 0xFFFF0000) | (uint_t)p);
#endif
}
static __device__ __forceinline__ long u2l(u2_ma v) {
    union { u2_ma u; long l; } x; x.u = v; return x.l;
}
// stored activation: u = y/ln2 = log2(0.5 + 2^(t-1)); -1 folded into bias.
static __device__ __forceinline__ float ssp_u(float accv) {
    return FLOG2(0.5f + FEXP2(accv));
}

// dtype auto-detection (validated round 4: inputs are f32; keep as insurance)
static __device__ __forceinline__ bool detect_is_f32(const ushort_t* probe) {
    __shared__ int flag;
    if (threadIdx.x == 0) flag = 0;
    __syncthreads();
    if (threadIdx.x < 256) {
        float v = fabsf(bf2f(probe[2 * threadIdx.x]));
        if (!(v <= 64.0f)) flag = 1;
    }
    __syncthreads();
    return flag != 0;
}
static __device__ __forceinline__ float in_elt(const void* p, int i, bool isf32) {
    return isf32 ? ((const float*)p)[i] : bf2f(((const ushort_t*)p)[i]);
}

// ---------------- weight prep (80 wg: layer L = bid>>2, quarter = bid&3) ----------------
// blob[L]: row m (out-feature) * 128 fp8 bytes; chunk c=k>>3 (8 B) at
// m*128 + 8*((k>>3)^(m&15)) + (k&7). Dword-wise with HW cvt_pk (RNE).
// L==0: W prescaled by log2e. bias = b*log2e - 1.
__global__ void prep_weights(const void* __restrict__ iW, const void* __restrict__ iB,
                             const void* __restrict__ oW, const void* __restrict__ oB)
{
    const bool isf32 = detect_is_f32((const ushort_t*)iW);
    const int L = blockIdx.x >> 2;      // 0..19
    const int qr = blockIdx.x & 3;      // dword-quarter
    const int b = L >> 2, li = L & 3;
    const void* srcW = (li < 2) ? iW : oW;
    const void* srcB = (li < 2) ? iB : oB;
    const int lyr = (li < 2) ? (b * 2 + li) : (b * 2 + li - 2);
    const int wofs = lyr * 16384;
    const int bofs = lyr * 128;
    uint8_t* blob = g_blob + (size_t)L * BLOB_BYTES;
    uint_t* dw = (uint_t*)blob;
    float*  db = (float*)(blob + BLOB_W_BYTES);
    const float sc = (L == 0) ? LOG2E : 1.0f;
    for (int t = threadIdx.x; t < 1024; t += blockDim.x) {
        int d = qr * 1024 + t;          // dword id: n = d&127, k-group kg = d>>7
        int n = d & 127, kg = d >> 7;   // k0 = kg*4
        float w0 = sc * in_elt(srcW, wofs + (kg * 4 + 0) * 128 + n, isf32);
        float w1 = sc * in_elt(srcW, wofs + (kg * 4 + 1) * 128 + n, isf32);
        float w2 = sc * in_elt(srcW, wofs + (kg * 4 + 2) * 128 + n, isf32);
        float w3 = sc * in_elt(srcW, wofs + (kg * 4 + 3) * 128 + n, isf32);
        int w = cvtpk2<false>(w0, w1, 0);
        w = cvtpk2<true>(w2, w3, w);
        dw[n * 32 + 2 * ((kg >> 1) ^ (n & 15)) + (kg & 1)] = (uint_t)w;
    }
    if (qr == 0)
        for (int m = threadIdx.x; m < 128; m += blockDim.x)
            db[m] = in_elt(srcB, bofs + m, isf32) * LOG2E - 1.0f;
}

// canonical f32 copies + accumulator zeroing
__global__ void prep_misc(const void* __restrict__ R, const void* __restrict__ oWf,
                          const void* __restrict__ oBf, const void* __restrict__ scales,
                          const void* __restrict__ shifts, const void* __restrict__ iW)
{
    const bool isf32 = detect_is_f32((const ushort_t*)iW);
    const int t = blockIdx.x * 256 + threadIdx.x;
    if (t < NBLK * NA * 2) g_outs[t] = 0.0f;
    if (t == 0)          g_nh[0]  = 0.0f;
    if (t < NA * 3)      g_Rf[t]   = in_elt(R, t, isf32);
    if (t < NBLK * 256)  g_oWfF[t] = LN2 * in_elt(oWf, t, isf32);
    if (t < NBLK * 2)    g_oBfF[t] = in_elt(oBf, t, isf32);
    if (t < 190)         g_scF[t]  = in_elt(scales, t, isf32);
    if (t < 190)         g_shF[t]  = in_elt(shifts, t, isf32);
}

// ---------------- fused per-pair MLP, fp8, BARRIER-FREE (L1-resident weights) --------
// wg = 256 = 4 independent waves x 32 pairs. A-frags are read directly from
// g_blob: the 16.5 KB layer blob fits per-CU L1 (32 KB) and all co-resident
// waves read the same layer in lockstep-ish order -> L1-hit loads whose
// latency pipelines under the 64 MFMAs + epilogue. No weight LDS, no
// __syncthreads anywhere in the layer loop. LDS = 4 x 4 KB wave-private act.
// acc[2][8] = 64 AGPR; bias rides as C-operand of the kt=0 MFMA.
// launch_bounds(256,3): 170-reg cap, demand ~140 -> no spill (round-11 lesson).
__global__ __launch_bounds__(256, 3)
void pairs_mlp_kernel(const int* __restrict__ idx_i,
                      const int* __restrict__ idx_j,
                      float* __restrict__ out_rij)       // d_out + 20000 (f32)
{
    __shared__ u2_ma act_all[4 * 512];       // 4 waves x (32 rows x 16 chunks of 8B)

    const int wave = threadIdx.x >> 6;
    const int lane = threadIdx.x & 63;
    u2_ma* act = act_all + wave * 512;

    const int pp = lane & 31;           // pair owned (both half-waves mirror)
    const int p0 = blockIdx.x * 128 + wave * 32;
    const int p = p0 + pp;
    const bool valid = (p < NP);

    // ---- phase 0: rij + radial basis, built DIRECTLY into fp8 B-frag regs ----
    int ai = 0, aj = 0;
    if (valid) { ai = idx_i[p]; aj = idx_j[p]; }
    float xi0 = g_Rf[3 * ai + 0], xi1 = g_Rf[3 * ai + 1], xi2 = g_Rf[3 * ai + 2];
    float xj0 = g_Rf[3 * aj + 0], xj1 = g_Rf[3 * aj + 1], xj2 = g_Rf[3 * aj + 2];
    float dx = xj0 - xi0, dy = xj1 - xi1, dz = xj2 - xi2;
    float rij = sqrtf(dx * dx + dy * dy + dz * dz + 1e-12f);
    if (lane < 32 && valid) out_rij[p] = rij;

    float fcut = 0.0f;
    if (valid && rij < 10.0f) {
        float xc = rij * 0.1f;
        float x3 = xc * xc * xc;
        fcut = 1.0f + x3 * (-10.0f + xc * (15.0f - 6.0f * xc));
    }
    const float mu0 = 4.5399929762484854e-05f;
    const float dmu = (1.0f - mu0) / 127.0f;
    const float wc = (2.0f / 128.0f) * (1.0f - mu0);
    const float NW2 = -(1.0f / (wc * wc)) * LOG2E;
    float er = FEXP2(-rij * LOG2E);

    const int q = lane >> 4;        // quad
    const int l15 = lane & 15;
    const int aseg = valid ? ai : -1;   // sentinel: invalid pairs never merge/fire

    // B-frag carry regs: bfrX[nt][kt] = x[pair nt*16+l15][k=kt*32+q*8 .. +7] fp8
    u2_ma bfrX[2][4];
    {
        float er_n[2], fc_n[2];
        er_n[0] = __shfl(er, l15, 64);      fc_n[0] = __shfl(fcut, l15, 64);
        er_n[1] = __shfl(er, 16 + l15, 64); fc_n[1] = __shfl(fcut, 16 + l15, 64);
#pragma unroll
        for (int nt = 0; nt < 2; ++nt)
#pragma unroll
            for (int kt = 0; kt < 4; ++kt) {
                float v[8];
#pragma unroll
                for (int jj = 0; jj < 8; ++jj) {
                    int g = kt * 32 + q * 8 + jj;
                    float mu = mu0 + (float)g * dmu;
                    float e0 = er_n[nt] - mu;
                    v[jj] = fc_n[nt] * FEXP2(NW2 * e0 * e0);
                }
                int w0 = cvtpk2<false>(v[0], v[1], 0);
                w0 = cvtpk2<true>(v[2], v[3], w0);
                int w1 = cvtpk2<false>(v[4], v[5], 0);
                w1 = cvtpk2<true>(v[6], v[7], w1);
                bfrX[nt][kt].x = (uint_t)w0;
                bfrX[nt][kt].y = (uint_t)w1;
            }
    }

    for (int blk = 0; blk < NBLK; ++blk) {
#pragma unroll
        for (int li = 0; li < 4; ++li) {
            const int L = blk * 4 + li;
            const u2_ma* wg2 = (const u2_ma*)(g_blob + (size_t)L * BLOB_BYTES);
            const float* bb = (const float*)(g_blob + (size_t)L * BLOB_BYTES + BLOB_W_BYTES);

            // biases as C-operand of kt=0 MFMA (b*log2e - 1 pre-folded; L1-hit)
            f32x4 bias[8];
#pragma unroll
            for (int mt = 0; mt < 8; ++mt)
                bias[mt] = *(const f32x4*)(bb + mt * 16 + q * 4);

            f32x4 acc[2][8];
#pragma unroll
            for (int kt = 0; kt < 4; ++kt) {
                const int cc = kt * 4 + q;
                u2_ma b0, b1;
                if (li == 0) {
                    b0 = bfrX[0][kt];
                    b1 = bfrX[1][kt];
                } else {
                    b0 = act[(l15) * 16 + (cc ^ l15)];
                    b1 = act[(16 + l15) * 16 + (cc ^ l15)];
                    if (li == 2) { bfrX[0][kt] = b0; bfrX[1][kt] = b1; }  // carry x
                }
                const long lb0 = u2l(b0), lb1 = u2l(b1);
#pragma unroll
                for (int mt = 0; mt < 8; ++mt) {
                    // A-frag straight from L1-resident blob (no LDS staging)
                    const long la = u2l(wg2[(mt * 16 + l15) * 16 + (cc ^ l15)]);
                    acc[0][mt] = __builtin_amdgcn_mfma_f32_16x16x32_fp8_fp8(
                        la, lb0, (kt == 0) ? bias[mt] : acc[0][mt], 0, 0, 0);
                    acc[1][mt] = __builtin_amdgcn_mfma_f32_16x16x32_fp8_fp8(
                        la, lb1, (kt == 0) ? bias[mt] : acc[1][mt], 0, 0, 0);
                }
            }

            if (li < 3) {
                // ssp + fp8 pack + in-place LDS write (wave-private region; all
                // this layer's ds_reads precede these writes in program order)
#pragma unroll
                for (int mt = 0; mt < 8; ++mt) {
                    const int c = mt * 2 + (q >> 1);   // feature chunk (8 fp8)
#pragma unroll
                    for (int nt = 0; nt < 2; ++nt) {
                        float u0 = ssp_u(acc[nt][mt][0]);
                        float u1 = ssp_u(acc[nt][mt][1]);
                        float u2 = ssp_u(acc[nt][mt][2]);
                        float u3 = ssp_u(acc[nt][mt][3]);
                        int w = cvtpk2<false>(u0, u1, 0);
                        w = cvtpk2<true>(u2, u3, w);
                        const int rp = nt * 16 + l15;
                        ((u1_ma*)&act[rp * 16 + (c ^ (rp & 15))])[q & 1] = (uint_t)w;
                    }
                }
            } else {
                // head: out_e = u3 @ (ln2*oWf) + oBf, then sorted-segment reduction
                const float* hw = g_oWfF + blk * 256;
                const float ob0 = g_oBfF[blk * 2 + 0];
                const float ob1 = g_oBfF[blk * 2 + 1];
                float hs[2][2];
#pragma unroll
                for (int nt = 0; nt < 2; ++nt) {
                    float h0 = 0.f, h1 = 0.f;
#pragma unroll
                    for (int mt = 0; mt < 8; ++mt) {
#pragma unroll
                        for (int rr = 0; rr < 4; ++rr) {
                            float u = ssp_u(acc[nt][mt][rr]);
                            const int f = mt * 16 + q * 4 + rr;
                            h0 = fmaf(u, hw[f * 2 + 0], h0);
                            h1 = fmaf(u, hw[f * 2 + 1], h1);
                        }
                    }
                    h0 += __shfl_xor(h0, 16, 64);
                    h0 += __shfl_xor(h0, 32, 64);
                    h1 += __shfl_xor(h1, 16, 64);
                    h1 += __shfl_xor(h1, 32, 64);
                    hs[nt][0] = h0; hs[nt][1] = h1;
                }
                float c0v = (pp < 16) ? hs[0][0] : hs[1][0];
                float c1v = (pp < 16) ? hs[0][1] : hs[1][1];
                c0v += ob0; c1v += ob1;
                // segmented inclusive scan over the 32 sorted pairs (runs contiguous)
#pragma unroll
                for (int d = 1; d < 32; d <<= 1) {
                    float t0 = __shfl_up(c0v, d, 64);
                    float t1 = __shfl_up(c1v, d, 64);
                    int   an = __shfl_up(aseg, d, 64);
                    if (pp >= d && an == aseg) { c0v += t0; c1v += t1; }
                }
                int ain = __shfl_down(aseg, 1, 64);
                bool tail = (pp == 31) || (ain != aseg);
                if (lane < 32 && valid && tail) {
                    atomicAdd(&g_outs[(blk * NA + aseg) * 2 + 0], c0v);
                    atomicAdd(&g_outs[(blk * NA + aseg) * 2 + 1], c1v);
                }
            }
        }
    }
}

// ---------------- finalize: scale/shift + nhloss reduction ----------------
__global__ void finalize_kernel(const int* __restrict__ Z,
                                float* __restrict__ out_atoms)   // d_out (f32)
{
    __shared__ float red[256];
    const int a = blockIdx.x * 256 + threadIdx.x;
    float s = 0.f;
    if (a < NA) {
        float v[NBLK][2];
        float t0 = 0.f, t1 = 0.f;
#pragma unroll
        for (int b = 0; b < NBLK; ++b) {
            v[b][0] = g_outs[(b * NA + a) * 2 + 0];
            v[b][1] = g_outs[(b * NA + a) * 2 + 1];
            t0 += v[b][0]; t1 += v[b][1];
        }
        const int z = Z[a];
        out_atoms[a * 2 + 0] = t0 * g_scF[z]      + g_shF[z];
        out_atoms[a * 2 + 1] = t1 * g_scF[95 + z] + g_shF[95 + z];
#pragma unroll
        for (int b = 1; b < NBLK; ++b)
#pragma unroll
            for (int o = 0; o < 2; ++o) {
                float x2 = v[b][o] * v[b][o];
                float p2 = v[b - 1][o] * v[b - 1][o];
                s += x2 / (x2 + p2 + 1e-7f);
            }
    }
    red[threadIdx.x] = s;
    __syncthreads();
    for (int st = 128; st > 0; st >>= 1) {
        if (threadIdx.x < st) red[threadIdx.x] += red[threadIdx.x + st];
        __syncthreads();
    }
    if (threadIdx.x == 0) atomicAdd(&g_nh[0], red[0]);
}

__global__ void nh_write(float* __restrict__ out_nh)
{
    out_nh[0] = g_nh[0] * (1.0f / 20000.0f);
}

// ---------------- launch ----------------
extern "C" void kernel_launch(void* const* d_in, const int* in_sizes, int n_in,
                              void* d_out, int out_size, void* d_ws, size_t ws_size,
                              hipStream_t stream)
{
    const int* Z     = (const int*)d_in[0];
    const void* R    = d_in[1];
    const int* idx_i = (const int*)d_in[2];
    const int* idx_j = (const int*)d_in[3];
    const void* iW   = d_in[4];
    const void* iB   = d_in[5];
    const void* oW   = d_in[6];
    const void* oB   = d_in[7];
    const void* oWf  = d_in[8];
    const void* oBf  = d_in[9];
    const void* scales = d_in[10];
    const void* shifts = d_in[11];

    float* out_f = (float*)d_out;   // [0,20000): outputs  [20000,270000): rij  [270000]: nhloss

    prep_weights<<<NL * 4, 256, 0, stream>>>(iW, iB, oW, oB);
    prep_misc<<<(NBLK * NA * 2 + 255) / 256, 256, 0, stream>>>(R, oWf, oBf, scales, shifts, iW);
    pairs_mlp_kernel<<<(NP + 127) / 128, 256, 0, stream>>>(idx_i, idx_j, out_f + 2 * NA);
    finalize_kernel<<<(NA + 255) / 256, 256, 0, stream>>>(Z, out_f);
    nh_write<<<1, 1, 0, stream>>>(out_f + 2 * NA + NP);
}

// Round 16
// 289.014 us; speedup vs baseline: 1.4788x; 1.4788x over previous
//
#include <hip/hip_runtime.h>
#include <stdint.h>

// ---------------- problem constants ----------------
#define NP   250000
#define NA   10000
#define NBLK 5
#define NL   20            // 5 blocks x (2 iW + 2 oW) layers
#define BLOB_W_BYTES 16384               // 128x128 fp8 e4m3, row=out-feature, XOR-swizzled
#define BLOB_BYTES   16896               // + 128 fp32 folded biases (512 B)

#define LOG2E 1.4426950408889634f
#define LN2   0.6931471805599453f

typedef float  f32x4  __attribute__((ext_vector_type(4)));
typedef unsigned short ushort_t;
typedef unsigned int   uint_t;
typedef int4  i4_ma __attribute__((may_alias));
typedef uint2 u2_ma __attribute__((may_alias));
typedef uint_t u1_ma __attribute__((may_alias));

// raw single-instruction transcendentals (v_exp_f32 / v_log_f32); args bounded
#if __has_builtin(__builtin_amdgcn_exp2f)
#define FEXP2(x) __builtin_amdgcn_exp2f(x)
#else
#define FEXP2(x) exp2f(x)
#endif
#if __has_builtin(__builtin_amdgcn_logf)
#define FLOG2(x) __builtin_amdgcn_logf(x)
#else
#define FLOG2(x) log2f(x)
#endif

// ---------------- static device scratch ----------------
__device__ uint8_t g_blob[NL * BLOB_BYTES];   // swizzled fp8 weights + folded f32 biases
__device__ float   g_outs[NBLK * NA * 2];     // per-block per-atom segment sums
__device__ float   g_nh[1];
__device__ unsigned g_done;
__device__ float   g_Rf[NA * 3];
__device__ float   g_oWfF[NBLK * 128 * 2];    // ln2-prescaled head weights
__device__ float   g_oBfF[NBLK * 2];          // head biases (unmodified)
__device__ float   g_scF[190];
__device__ float   g_shF[190];

static __device__ __forceinline__ float bf2f(ushort_t u) {
    return __uint_as_float(((uint_t)u) << 16);
}
// e4m3fn (OCP) encoder — fallback only
static __device__ uint8_t f2fp8(float f) {
    uint_t u = __float_as_uint(f);
    uint8_t s = (uint8_t)((u >> 24) & 0x80);
    float af = fabsf(f);
    if (af != af) return (uint8_t)(s | 0x7F);
    if (af > 448.0f) return (uint8_t)(s | 0x7E);
    int e = (int)((u >> 23) & 0xFF) - 127;
    uint_t m = u & 0x7FFFFFu;
    if (e >= -6) {
        uint_t mant = m >> 20;
        uint_t rest = m & 0xFFFFFu;
        if (rest > 0x80000u || (rest == 0x80000u && (mant & 1u))) mant++;
        uint_t ee = (uint_t)(e + 7);
        if (mant == 8u) { mant = 0u; ee++; }
        if (ee > 15u || (ee == 15u && mant > 6u)) return (uint8_t)(s | 0x7E);
        return (uint8_t)(s | (ee << 3) | mant);
    }
    int qq = (int)rintf(af * 512.0f);      // subnormal: grid 2^-9
    if (qq > 7) return (uint8_t)(s | 0x08);
    return (uint8_t)(s | (uint_t)qq);
}
// pack 2 f32 -> 2 fp8 bytes into low/high half of a dword (HI = immediate)
template <bool HI>
static __device__ __forceinline__ int cvtpk2(float a, float b, int old) {
#if __has_builtin(__builtin_amdgcn_cvt_pk_fp8_f32)
    return __builtin_amdgcn_cvt_pk_fp8_f32(a, b, old, HI);
#else
    int p = (int)f2fp8(a) | ((int)f2fp8(b) << 8);
    return HI ? (int)((old & 0x0000FFFF) | ((uint_t)p << 16))
              : (int)((old & 0xFFFF0000) | (uint_t)p);
#endif
}
static __device__ __forceinline__ long u2l(u2_ma v) {
    union { u2_ma u; long l; } x; x.u = v; return x.l;
}
// stored activation: u = y/ln2 = log2(0.5 + 2^(t-1)); -1 folded into bias.
static __device__ __forceinline__ float ssp_u(float accv) {
    return FLOG2(0.5f + FEXP2(accv));
}

// dtype auto-detection (validated round 4: inputs are f32; keep as insurance)
static __device__ __forceinline__ bool detect_is_f32(const ushort_t* probe) {
    __shared__ int flag;
    if (threadIdx.x == 0) flag = 0;
    __syncthreads();
    if (threadIdx.x < 256) {
        float v = fabsf(bf2f(probe[2 * threadIdx.x]));
        if (!(v <= 64.0f)) flag = 1;
    }
    __syncthreads();
    return flag != 0;
}
static __device__ __forceinline__ float in_elt(const void* p, int i, bool isf32) {
    return isf32 ? ((const float*)p)[i] : bf2f(((const ushort_t*)p)[i]);
}

// ---------------- merged prep: weights (blocks 0..79) + misc (blocks 80..470) --------
// blob[L]: row m (out-feature) * 128 fp8 bytes; chunk c=k>>3 (8 B) at
// m*128 + 8*((k>>3)^(m&15)) + (k&7). Dword-wise with HW cvt_pk (RNE).
// L==0: W prescaled by log2e. bias = b*log2e - 1.
__global__ void prep_kernel(const void* __restrict__ iW, const void* __restrict__ iB,
                            const void* __restrict__ oW, const void* __restrict__ oB,
                            const void* __restrict__ R, const void* __restrict__ oWf,
                            const void* __restrict__ oBf, const void* __restrict__ scales,
                            const void* __restrict__ shifts)
{
    const bool isf32 = detect_is_f32((const ushort_t*)iW);
    if (blockIdx.x < 80) {
        const int L = blockIdx.x >> 2;      // 0..19
        const int qr = blockIdx.x & 3;      // dword-quarter
        const int b = L >> 2, li = L & 3;
        const void* srcW = (li < 2) ? iW : oW;
        const void* srcB = (li < 2) ? iB : oB;
        const int lyr = (li < 2) ? (b * 2 + li) : (b * 2 + li - 2);
        const int wofs = lyr * 16384;
        const int bofs = lyr * 128;
        uint8_t* blob = g_blob + (size_t)L * BLOB_BYTES;
        uint_t* dw = (uint_t*)blob;
        float*  db = (float*)(blob + BLOB_W_BYTES);
        const float sc = (L == 0) ? LOG2E : 1.0f;
        for (int t = threadIdx.x; t < 1024; t += blockDim.x) {
            int d = qr * 1024 + t;          // dword id: n = d&127, k-group kg = d>>7
            int n = d & 127, kg = d >> 7;   // k0 = kg*4
            float w0 = sc * in_elt(srcW, wofs + (kg * 4 + 0) * 128 + n, isf32);
            float w1 = sc * in_elt(srcW, wofs + (kg * 4 + 1) * 128 + n, isf32);
            float w2 = sc * in_elt(srcW, wofs + (kg * 4 + 2) * 128 + n, isf32);
            float w3 = sc * in_elt(srcW, wofs + (kg * 4 + 3) * 128 + n, isf32);
            int w = cvtpk2<false>(w0, w1, 0);
            w = cvtpk2<true>(w2, w3, w);
            dw[n * 32 + 2 * ((kg >> 1) ^ (n & 15)) + (kg & 1)] = (uint_t)w;
        }
        if (qr == 0)
            for (int m = threadIdx.x; m < 128; m += blockDim.x)
                db[m] = in_elt(srcB, bofs + m, isf32) * LOG2E - 1.0f;
    } else {
        const int t = (blockIdx.x - 80) * 256 + threadIdx.x;
        if (t < NBLK * NA * 2) g_outs[t] = 0.0f;
        if (t == 0) { g_nh[0] = 0.0f; g_done = 0u; }
        if (t < NA * 3)      g_Rf[t]   = in_elt(R, t, isf32);
        if (t < NBLK * 256)  g_oWfF[t] = LN2 * in_elt(oWf, t, isf32);
        if (t < NBLK * 2)    g_oBfF[t] = in_elt(oBf, t, isf32);
        if (t < 190)         g_scF[t]  = in_elt(scales, t, isf32);
        if (t < 190)         g_shF[t]  = in_elt(shifts, t, isf32);
    }
}

// ---------------- fused per-pair MLP, fp8, double-buffered weight staging ------------
// wg = 256 = 4 waves x 32 pairs (round-12 validated shape). Per layer: prefetch
// L+1's 16 KB into 4 int4 regs at layer start (latency hides under compute),
// compute layer L from w_lds[L&1], ds_write the prefetch into w_lds[(L+1)&1]
// (unread -> no pre-barrier needed), ONE __syncthreads at layer end (nothing
// in flight -> cheap). Bias rides as C-operand of the kt=0 MFMA. LDS = 2x16 KB
// weights + 4x4 KB act = 48 KB -> 3 wg/CU (VGPR binds at 3 anyway).
// launch_bounds(256,3): 170-reg cap; demand ~160 (80 arch +16 prefetch + 64 acc).
__global__ __launch_bounds__(256, 3)
void pairs_mlp_kernel(const int* __restrict__ idx_i,
                      const int* __restrict__ idx_j,
                      float* __restrict__ out_rij)       // d_out + 20000 (f32)
{
    __shared__ i4_ma w_lds[2048];            // 2 x 16 KB fp8 weight buffers
    __shared__ u2_ma act_all[4 * 512];       // 4 waves x (32 rows x 16 chunks of 8B)

    // issue layer-0 weight loads immediately (latency hides under phase 0)
    const i4_ma* gW0 = (const i4_ma*)g_blob;
    i4_ma s0 = gW0[threadIdx.x];
    i4_ma s1 = gW0[threadIdx.x + 256];
    i4_ma s2 = gW0[threadIdx.x + 512];
    i4_ma s3 = gW0[threadIdx.x + 768];

    const int wave = threadIdx.x >> 6;
    const int lane = threadIdx.x & 63;
    u2_ma* act = act_all + wave * 512;

    const int pp = lane & 31;           // pair owned (both half-waves mirror)
    const int p0 = blockIdx.x * 128 + wave * 32;
    const int p = p0 + pp;
    const bool valid = (p < NP);

    // ---- phase 0: rij + radial basis, built DIRECTLY into fp8 B-frag regs ----
    int ai = 0, aj = 0;
    if (valid) { ai = idx_i[p]; aj = idx_j[p]; }
    float xi0 = g_Rf[3 * ai + 0], xi1 = g_Rf[3 * ai + 1], xi2 = g_Rf[3 * ai + 2];
    float xj0 = g_Rf[3 * aj + 0], xj1 = g_Rf[3 * aj + 1], xj2 = g_Rf[3 * aj + 2];
    float dx = xj0 - xi0, dy = xj1 - xi1, dz = xj2 - xi2;
    float rij = sqrtf(dx * dx + dy * dy + dz * dz + 1e-12f);
    if (lane < 32 && valid) out_rij[p] = rij;

    float fcut = 0.0f;
    if (valid && rij < 10.0f) {
        float xc = rij * 0.1f;
        float x3 = xc * xc * xc;
        fcut = 1.0f + x3 * (-10.0f + xc * (15.0f - 6.0f * xc));
    }
    const float mu0 = 4.5399929762484854e-05f;
    const float dmu = (1.0f - mu0) / 127.0f;
    const float wc = (2.0f / 128.0f) * (1.0f - mu0);
    const float NW2 = -(1.0f / (wc * wc)) * LOG2E;
    float er = FEXP2(-rij * LOG2E);

    const int q = lane >> 4;        // quad
    const int l15 = lane & 15;
    const int aseg = valid ? ai : -1;   // sentinel: invalid pairs never merge/fire

    // B-frag carry regs: bfrX[nt][kt] = x[pair nt*16+l15][k=kt*32+q*8 .. +7] fp8
    u2_ma bfrX[2][4];
    {
        float er_n[2], fc_n[2];
        er_n[0] = __shfl(er, l15, 64);      fc_n[0] = __shfl(fcut, l15, 64);
        er_n[1] = __shfl(er, 16 + l15, 64); fc_n[1] = __shfl(fcut, 16 + l15, 64);
#pragma unroll
        for (int nt = 0; nt < 2; ++nt)
#pragma unroll
            for (int kt = 0; kt < 4; ++kt) {
                float v[8];
#pragma unroll
                for (int jj = 0; jj < 8; ++jj) {
                    int g = kt * 32 + q * 8 + jj;
                    float mu = mu0 + (float)g * dmu;
                    float e0 = er_n[nt] - mu;
                    v[jj] = fc_n[nt] * FEXP2(NW2 * e0 * e0);
                }
                int w0 = cvtpk2<false>(v[0], v[1], 0);
                w0 = cvtpk2<true>(v[2], v[3], w0);
                int w1 = cvtpk2<false>(v[4], v[5], 0);
                w1 = cvtpk2<true>(v[6], v[7], w1);
                bfrX[nt][kt].x = (uint_t)w0;
                bfrX[nt][kt].y = (uint_t)w1;
            }
    }

    // stage layer 0 into buffer 0
    w_lds[threadIdx.x]       = s0;
    w_lds[threadIdx.x + 256] = s1;
    w_lds[threadIdx.x + 512] = s2;
    w_lds[threadIdx.x + 768] = s3;
    __syncthreads();

    for (int blk = 0; blk < NBLK; ++blk) {
#pragma unroll
        for (int li = 0; li < 4; ++li) {
            const int L = blk * 4 + li;
            const bool hasNext = (L + 1 < NL);

            // ---- prefetch next layer's weights into regs (latency hidden) ----
            i4_ma pf0, pf1, pf2, pf3;
            if (hasNext) {
                const i4_ma* gWn = (const i4_ma*)(g_blob + (size_t)(L + 1) * BLOB_BYTES);
                pf0 = gWn[threadIdx.x];
                pf1 = gWn[threadIdx.x + 256];
                pf2 = gWn[threadIdx.x + 512];
                pf3 = gWn[threadIdx.x + 768];
            }

            const u2_ma* wl2 = (const u2_ma*)(w_lds + (li & 1) * 1024);
            const float* bb = (const float*)(g_blob + (size_t)L * BLOB_BYTES + BLOB_W_BYTES);

            // biases as C-operand of the kt=0 MFMA (b*log2e - 1 pre-folded)
            f32x4 bias[8];
#pragma unroll
            for (int mt = 0; mt < 8; ++mt)
                bias[mt] = *(const f32x4*)(bb + mt * 16 + q * 4);

            f32x4 acc[2][8];
#pragma unroll
            for (int kt = 0; kt < 4; ++kt) {
                const int cc = kt * 4 + q;
                u2_ma b0, b1;
                if (li == 0) {
                    b0 = bfrX[0][kt];
                    b1 = bfrX[1][kt];
                } else {
                    b0 = act[(l15) * 16 + (cc ^ l15)];
                    b1 = act[(16 + l15) * 16 + (cc ^ l15)];
                    if (li == 2) { bfrX[0][kt] = b0; bfrX[1][kt] = b1; }  // carry x
                }
                const long lb0 = u2l(b0), lb1 = u2l(b1);
#pragma unroll
                for (int mt = 0; mt < 8; ++mt) {
                    const long la = u2l(wl2[(mt * 16 + l15) * 16 + (cc ^ l15)]);
                    acc[0][mt] = __builtin_amdgcn_mfma_f32_16x16x32_fp8_fp8(
                        la, lb0, (kt == 0) ? bias[mt] : acc[0][mt], 0, 0, 0);
                    acc[1][mt] = __builtin_amdgcn_mfma_f32_16x16x32_fp8_fp8(
                        la, lb1, (kt == 0) ? bias[mt] : acc[1][mt], 0, 0, 0);
                }
            }

            if (li < 3) {
                // ssp + fp8 pack + in-place LDS write (wave-private region; all
                // this layer's ds_reads precede these writes in program order)
#pragma unroll
                for (int mt = 0; mt < 8; ++mt) {
                    const int c = mt * 2 + (q >> 1);   // feature chunk (8 fp8)
#pragma unroll
                    for (int nt = 0; nt < 2; ++nt) {
                        float u0 = ssp_u(acc[nt][mt][0]);
                        float u1 = ssp_u(acc[nt][mt][1]);
                        float u2 = ssp_u(acc[nt][mt][2]);
                        float u3 = ssp_u(acc[nt][mt][3]);
                        int w = cvtpk2<false>(u0, u1, 0);
                        w = cvtpk2<true>(u2, u3, w);
                        const int rp = nt * 16 + l15;
                        ((u1_ma*)&act[rp * 16 + (c ^ (rp & 15))])[q & 1] = (uint_t)w;
                    }
                }
            } else {
                // head: out_e = u3 @ (ln2*oWf) + oBf, then sorted-segment reduction
                const float* hw = g_oWfF + blk * 256;
                const float ob0 = g_oBfF[blk * 2 + 0];
                const float ob1 = g_oBfF[blk * 2 + 1];
                float hs[2][2];
#pragma unroll
                for (int nt = 0; nt < 2; ++nt) {
                    float h0 = 0.f, h1 = 0.f;
#pragma unroll
                    for (int mt = 0; mt < 8; ++mt) {
#pragma unroll
                        for (int rr = 0; rr < 4; ++rr) {
                            float u = ssp_u(acc[nt][mt][rr]);
                            const int f = mt * 16 + q * 4 + rr;
                            h0 = fmaf(u, hw[f * 2 + 0], h0);
                            h1 = fmaf(u, hw[f * 2 + 1], h1);
                        }
                    }
                    h0 += __shfl_xor(h0, 16, 64);
                    h0 += __shfl_xor(h0, 32, 64);
                    h1 += __shfl_xor(h1, 16, 64);
                    h1 += __shfl_xor(h1, 32, 64);
                    hs[nt][0] = h0; hs[nt][1] = h1;
                }
                float c0v = (pp < 16) ? hs[0][0] : hs[1][0];
                float c1v = (pp < 16) ? hs[0][1] : hs[1][1];
                c0v += ob0; c1v += ob1;
                // segmented inclusive scan over the 32 sorted pairs (runs contiguous)
#pragma unroll
                for (int d = 1; d < 32; d <<= 1) {
                    float t0 = __shfl_up(c0v, d, 64);
                    float t1 = __shfl_up(c1v, d, 64);
                    int   an = __shfl_up(aseg, d, 64);
                    if (pp >= d && an == aseg) { c0v += t0; c1v += t1; }
                }
                int ain = __shfl_down(aseg, 1, 64);
                bool tail = (pp == 31) || (ain != aseg);
                if (lane < 32 && valid && tail) {
                    atomicAdd(&g_outs[(blk * NA + aseg) * 2 + 0], c0v);
                    atomicAdd(&g_outs[(blk * NA + aseg) * 2 + 1], c1v);
                }
            }

            // ---- stage L+1 into the other buffer (nobody reads it yet) ----
            if (hasNext) {
                i4_ma* dstb = w_lds + ((li + 1) & 1) * 1024;
                dstb[threadIdx.x]       = pf0;
                dstb[threadIdx.x + 256] = pf1;
                dstb[threadIdx.x + 512] = pf2;
                dstb[threadIdx.x + 768] = pf3;
                __syncthreads();          // cheap: staging writes already local
            }
        }
    }
}

// ---------------- finalize: scale/shift + nhloss (last-block writes nh) ----------
__global__ void finalize_kernel(const int* __restrict__ Z,
                                float* __restrict__ out_atoms,   // d_out (f32)
                                float* __restrict__ out_nh)
{
    __shared__ float red[256];
    const int a = blockIdx.x * 256 + threadIdx.x;
    float s = 0.f;
    if (a < NA) {
        float v[NBLK][2];
        float t0 = 0.f, t1 = 0.f;
#pragma unroll
        for (int b = 0; b < NBLK; ++b) {
            v[b][0] = g_outs[(b * NA + a) * 2 + 0];
            v[b][1] = g_outs[(b * NA + a) * 2 + 1];
            t0 += v[b][0]; t1 += v[b][1];
        }
        const int z = Z[a];
        out_atoms[a * 2 + 0] = t0 * g_scF[z]      + g_shF[z];
        out_atoms[a * 2 + 1] = t1 * g_scF[95 + z] + g_shF[95 + z];
#pragma unroll
        for (int b = 1; b < NBLK; ++b)
#pragma unroll
            for (int o = 0; o < 2; ++o) {
                float x2 = v[b][o] * v[b][o];
                float p2 = v[b - 1][o] * v[b - 1][o];
                s += x2 / (x2 + p2 + 1e-7f);
            }
    }
    red[threadIdx.x] = s;
    __syncthreads();
    for (int st = 128; st > 0; st >>= 1) {
        if (threadIdx.x < st) red[threadIdx.x] += red[threadIdx.x + st];
        __syncthreads();
    }
    if (threadIdx.x == 0) {
        atomicAdd(&g_nh[0], red[0]);
        __threadfence();
        unsigned old = atomicAdd(&g_done, 1u);
        if (old == gridDim.x - 1) {
            float v = atomicAdd(&g_nh[0], 0.0f);   // device-scope coherent read
            out_nh[0] = v * (1.0f / 20000.0f);
        }
    }
}

// ---------------- launch ----------------
extern "C" void kernel_launch(void* const* d_in, const int* in_sizes, int n_in,
                              void* d_out, int out_size, void* d_ws, size_t ws_size,
                              hipStream_t stream)
{
    const int* Z     = (const int*)d_in[0];
    const void* R    = d_in[1];
    const int* idx_i = (const int*)d_in[2];
    const int* idx_j = (const int*)d_in[3];
    const void* iW   = d_in[4];
    const void* iB   = d_in[5];
    const void* oW   = d_in[6];
    const void* oB   = d_in[7];
    const void* oWf  = d_in[8];
    const void* oBf  = d_in[9];
    const void* scales = d_in[10];
    const void* shifts = d_in[11];

    float* out_f = (float*)d_out;   // [0,20000): outputs  [20000,270000): rij  [270000]: nhloss

    prep_kernel<<<80 + 391, 256, 0, stream>>>(iW, iB, oW, oB, R, oWf, oBf, scales, shifts);
    pairs_mlp_kernel<<<(NP + 127) / 128, 256, 0, stream>>>(idx_i, idx_j, out_f + 2 * NA);
    finalize_kernel<<<(NA + 255) / 256, 256, 0, stream>>>(Z, out_f, out_f + 2 * NA + NP);
}

// Round 17
// 268.005 us; speedup vs baseline: 1.5947x; 1.0784x over previous
//
#include <hip/hip_runtime.h>
#include <stdint.h>

// ---------------- problem constants ----------------
#define NP   250000
#define NA   10000
#define NBLK 5
#define NL   20            // 5 blocks x (2 iW + 2 oW) layers
#define BLOB_W_BYTES 16384               // 128x128 fp8 e4m3, row=out-feature, XOR-swizzled
#define BLOB_BYTES   16896               // + 128 fp32 folded biases (512 B)

#define LOG2E 1.4426950408889634f
#define LN2   0.6931471805599453f

typedef float  f32x4  __attribute__((ext_vector_type(4)));
typedef unsigned short ushort_t;
typedef unsigned int   uint_t;
typedef int4  i4_ma __attribute__((may_alias));
typedef uint2 u2_ma __attribute__((may_alias));
typedef uint_t u1_ma __attribute__((may_alias));

// raw single-instruction transcendentals (v_exp_f32 / v_log_f32); args bounded
#if __has_builtin(__builtin_amdgcn_exp2f)
#define FEXP2(x) __builtin_amdgcn_exp2f(x)
#else
#define FEXP2(x) exp2f(x)
#endif
#if __has_builtin(__builtin_amdgcn_logf)
#define FLOG2(x) __builtin_amdgcn_logf(x)
#else
#define FLOG2(x) log2f(x)
#endif

// ---------------- static device scratch ----------------
__device__ uint8_t g_blob[NL * BLOB_BYTES];   // swizzled fp8 weights + folded f32 biases
__device__ float   g_outs[NBLK * NA * 2];     // per-block per-atom segment sums
__device__ float   g_nh[1];
__device__ unsigned g_done;
__device__ float   g_Rf[NA * 3];
__device__ float   g_oWfF[NBLK * 128 * 2];    // ln2-prescaled head weights
__device__ float   g_oBfF[NBLK * 2];          // head biases (unmodified)
__device__ float   g_scF[190];
__device__ float   g_shF[190];

static __device__ __forceinline__ float bf2f(ushort_t u) {
    return __uint_as_float(((uint_t)u) << 16);
}
// e4m3fn (OCP) encoder — fallback only
static __device__ uint8_t f2fp8(float f) {
    uint_t u = __float_as_uint(f);
    uint8_t s = (uint8_t)((u >> 24) & 0x80);
    float af = fabsf(f);
    if (af != af) return (uint8_t)(s | 0x7F);
    if (af > 448.0f) return (uint8_t)(s | 0x7E);
    int e = (int)((u >> 23) & 0xFF) - 127;
    uint_t m = u & 0x7FFFFFu;
    if (e >= -6) {
        uint_t mant = m >> 20;
        uint_t rest = m & 0xFFFFFu;
        if (rest > 0x80000u || (rest == 0x80000u && (mant & 1u))) mant++;
        uint_t ee = (uint_t)(e + 7);
        if (mant == 8u) { mant = 0u; ee++; }
        if (ee > 15u || (ee == 15u && mant > 6u)) return (uint8_t)(s | 0x7E);
        return (uint8_t)(s | (ee << 3) | mant);
    }
    int qq = (int)rintf(af * 512.0f);      // subnormal: grid 2^-9
    if (qq > 7) return (uint8_t)(s | 0x08);
    return (uint8_t)(s | (uint_t)qq);
}
// pack 2 f32 -> 2 fp8 bytes into low/high half of a dword (HI = immediate)
template <bool HI>
static __device__ __forceinline__ int cvtpk2(float a, float b, int old) {
#if __has_builtin(__builtin_amdgcn_cvt_pk_fp8_f32)
    return __builtin_amdgcn_cvt_pk_fp8_f32(a, b, old, HI);
#else
    int p = (int)f2fp8(a) | ((int)f2fp8(b) << 8);
    return HI ? (int)((old & 0x0000FFFF) | ((uint_t)p << 16))
              : (int)((old & 0xFFFF0000) | (uint_t)p);
#endif
}
static __device__ __forceinline__ long u2l(u2_ma v) {
    union { u2_ma u; long l; } x; x.u = v; return x.l;
}
// stored activation: u = y/ln2 = log2(0.5 + 2^(t-1)); -1 folded into bias.
static __device__ __forceinline__ float ssp_u(float accv) {
    return FLOG2(0.5f + FEXP2(accv));
}

// dtype auto-detection (validated round 4: inputs are f32; keep as insurance)
static __device__ __forceinline__ bool detect_is_f32(const ushort_t* probe) {
    __shared__ int flag;
    if (threadIdx.x == 0) flag = 0;
    __syncthreads();
    if (threadIdx.x < 256) {
        float v = fabsf(bf2f(probe[2 * threadIdx.x]));
        if (!(v <= 64.0f)) flag = 1;
    }
    __syncthreads();
    return flag != 0;
}
static __device__ __forceinline__ float in_elt(const void* p, int i, bool isf32) {
    return isf32 ? ((const float*)p)[i] : bf2f(((const ushort_t*)p)[i]);
}

// ---------------- merged prep: weights (blocks 0..79) + misc (blocks 80..470) --------
// blob[L]: row m (out-feature) * 128 fp8 bytes; chunk c=k>>3 (8 B) at
// m*128 + 8*((k>>3)^(m&15)) + (k&7). Dword-wise with HW cvt_pk (RNE).
// L==0: W prescaled by log2e. bias = b*log2e - 1.
__global__ void prep_kernel(const void* __restrict__ iW, const void* __restrict__ iB,
                            const void* __restrict__ oW, const void* __restrict__ oB,
                            const void* __restrict__ R, const void* __restrict__ oWf,
                            const void* __restrict__ oBf, const void* __restrict__ scales,
                            const void* __restrict__ shifts)
{
    const bool isf32 = detect_is_f32((const ushort_t*)iW);
    if (blockIdx.x < 80) {
        const int L = blockIdx.x >> 2;      // 0..19
        const int qr = blockIdx.x & 3;      // dword-quarter
        const int b = L >> 2, li = L & 3;
        const void* srcW = (li < 2) ? iW : oW;
        const void* srcB = (li < 2) ? iB : oB;
        const int lyr = (li < 2) ? (b * 2 + li) : (b * 2 + li - 2);
        const int wofs = lyr * 16384;
        const int bofs = lyr * 128;
        uint8_t* blob = g_blob + (size_t)L * BLOB_BYTES;
        uint_t* dw = (uint_t*)blob;
        float*  db = (float*)(blob + BLOB_W_BYTES);
        const float sc = (L == 0) ? LOG2E : 1.0f;
        for (int t = threadIdx.x; t < 1024; t += blockDim.x) {
            int d = qr * 1024 + t;          // dword id: n = d&127, k-group kg = d>>7
            int n = d & 127, kg = d >> 7;   // k0 = kg*4
            float w0 = sc * in_elt(srcW, wofs + (kg * 4 + 0) * 128 + n, isf32);
            float w1 = sc * in_elt(srcW, wofs + (kg * 4 + 1) * 128 + n, isf32);
            float w2 = sc * in_elt(srcW, wofs + (kg * 4 + 2) * 128 + n, isf32);
            float w3 = sc * in_elt(srcW, wofs + (kg * 4 + 3) * 128 + n, isf32);
            int w = cvtpk2<false>(w0, w1, 0);
            w = cvtpk2<true>(w2, w3, w);
            dw[n * 32 + 2 * ((kg >> 1) ^ (n & 15)) + (kg & 1)] = (uint_t)w;
        }
        if (qr == 0)
            for (int m = threadIdx.x; m < 128; m += blockDim.x)
                db[m] = in_elt(srcB, bofs + m, isf32) * LOG2E - 1.0f;
    } else {
        const int t = (blockIdx.x - 80) * 256 + threadIdx.x;
        if (t < NBLK * NA * 2) g_outs[t] = 0.0f;
        if (t == 0) { g_nh[0] = 0.0f; g_done = 0u; }
        if (t < NA * 3)      g_Rf[t]   = in_elt(R, t, isf32);
        if (t < NBLK * 256)  g_oWfF[t] = LN2 * in_elt(oWf, t, isf32);
        if (t < NBLK * 2)    g_oBfF[t] = in_elt(oBf, t, isf32);
        if (t < 190)         g_scF[t]  = in_elt(scales, t, isf32);
        if (t < 190)         g_shF[t]  = in_elt(shifts, t, isf32);
    }
}

// ---------------- fused per-pair MLP, fp8 path, wg-shared weights ----------------
// ROUND-12 VALIDATED SHAPE (209 us): wg = 256 = 4 waves x 32 pairs. Per layer:
// barrier -> cooperative 16 KB weight stage -> barrier -> compute from LDS
// A-frags + wave-private 4 KB in-place act region. x2 carried across li2/li3
// in 8 VGPRs. LDS = 16 KB W + 4 x 4 KB act = 32 KB.
// launch_bounds(256,3): 170-reg cap; 80 VGPR + 64 acc = 144 -> no spill.
// (Rounds 13-16 tested 2-layer lump / 16 pairs/wave / no-LDS / reg-prefetch
// dbuf: ALL regressed. This is the local optimum shape.)
__global__ __launch_bounds__(256, 3)
void pairs_mlp_kernel(const int* __restrict__ idx_i,
                      const int* __restrict__ idx_j,
                      float* __restrict__ out_rij)       // d_out + 20000 (f32)
{
    __shared__ i4_ma w_lds[1024];            // 16 KB: fp8 weight blob of layer L
    __shared__ u2_ma act_all[4 * 512];       // 4 waves x (32 rows x 16 chunks of 8B)

    const int wave = threadIdx.x >> 6;
    const int lane = threadIdx.x & 63;
    u2_ma* act = act_all + wave * 512;
    const u2_ma* wl2 = (const u2_ma*)w_lds;

    const int pp = lane & 31;           // pair owned (both half-waves mirror)
    const int p0 = blockIdx.x * 128 + wave * 32;
    const int p = p0 + pp;
    const bool valid = (p < NP);

    // ---- phase 0: rij + radial basis, built DIRECTLY into fp8 B-frag regs ----
    int ai = 0, aj = 0;
    if (valid) { ai = idx_i[p]; aj = idx_j[p]; }
    float xi0 = g_Rf[3 * ai + 0], xi1 = g_Rf[3 * ai + 1], xi2 = g_Rf[3 * ai + 2];
    float xj0 = g_Rf[3 * aj + 0], xj1 = g_Rf[3 * aj + 1], xj2 = g_Rf[3 * aj + 2];
    float dx = xj0 - xi0, dy = xj1 - xi1, dz = xj2 - xi2;
    float rij = sqrtf(dx * dx + dy * dy + dz * dz + 1e-12f);
    if (lane < 32 && valid) out_rij[p] = rij;

    float fcut = 0.0f;
    if (valid && rij < 10.0f) {
        float xc = rij * 0.1f;
        float x3 = xc * xc * xc;
        fcut = 1.0f + x3 * (-10.0f + xc * (15.0f - 6.0f * xc));
    }
    const float mu0 = 4.5399929762484854e-05f;
    const float dmu = (1.0f - mu0) / 127.0f;
    const float wc = (2.0f / 128.0f) * (1.0f - mu0);
    const float NW2 = -(1.0f / (wc * wc)) * LOG2E;
    float er = FEXP2(-rij * LOG2E);

    const int q = lane >> 4;        // quad
    const int l15 = lane & 15;
    const int aseg = valid ? ai : -1;   // sentinel: invalid pairs never merge/fire

    // B-frag carry regs: bfrX[nt][kt] = x[pair nt*16+l15][k=kt*32+q*8 .. +7] fp8
    u2_ma bfrX[2][4];
    {
        float er_n[2], fc_n[2];
        er_n[0] = __shfl(er, l15, 64);      fc_n[0] = __shfl(fcut, l15, 64);
        er_n[1] = __shfl(er, 16 + l15, 64); fc_n[1] = __shfl(fcut, 16 + l15, 64);
#pragma unroll
        for (int nt = 0; nt < 2; ++nt)
#pragma unroll
            for (int kt = 0; kt < 4; ++kt) {
                float v[8];
#pragma unroll
                for (int jj = 0; jj < 8; ++jj) {
                    int g = kt * 32 + q * 8 + jj;
                    float mu = mu0 + (float)g * dmu;
                    float e0 = er_n[nt] - mu;
                    v[jj] = fc_n[nt] * FEXP2(NW2 * e0 * e0);
                }
                int w0 = cvtpk2<false>(v[0], v[1], 0);
                w0 = cvtpk2<true>(v[2], v[3], w0);
                int w1 = cvtpk2<false>(v[4], v[5], 0);
                w1 = cvtpk2<true>(v[6], v[7], w1);
                bfrX[nt][kt].x = (uint_t)w0;
                bfrX[nt][kt].y = (uint_t)w1;
            }
    }

    for (int blk = 0; blk < NBLK; ++blk) {
#pragma unroll
        for (int li = 0; li < 4; ++li) {
            const int L = blk * 4 + li;
            const i4_ma* gW = (const i4_ma*)(g_blob + (size_t)L * BLOB_BYTES);
            const float* bb = (const float*)(g_blob + (size_t)L * BLOB_BYTES + BLOB_W_BYTES);

            // ---- cooperative weight staging (all 4 waves) ----
            __syncthreads();              // everyone done reading W_{L-1}
#pragma unroll
            for (int it = 0; it < 4; ++it)
                w_lds[threadIdx.x + it * 256] = gW[threadIdx.x + it * 256];
            __syncthreads();

            // acc initialized to folded bias (b*log2e - 1)
            f32x4 acc[2][8];
#pragma unroll
            for (int mt = 0; mt < 8; ++mt) {
                const f32x4 bias = *(const f32x4*)(bb + mt * 16 + q * 4);
                acc[0][mt] = bias;
                acc[1][mt] = bias;
            }
#pragma unroll
            for (int kt = 0; kt < 4; ++kt) {
                const int cc = kt * 4 + q;
                u2_ma b0, b1;
                if (li == 0) {
                    b0 = bfrX[0][kt];
                    b1 = bfrX[1][kt];
                } else {
                    b0 = act[(l15) * 16 + (cc ^ l15)];
                    b1 = act[(16 + l15) * 16 + (cc ^ l15)];
                    if (li == 2) { bfrX[0][kt] = b0; bfrX[1][kt] = b1; }  // carry x
                }
                const long lb0 = u2l(b0), lb1 = u2l(b1);
#pragma unroll
                for (int mt = 0; mt < 8; ++mt) {
                    const long la = u2l(wl2[(mt * 16 + l15) * 16 + (cc ^ l15)]);
                    acc[0][mt] = __builtin_amdgcn_mfma_f32_16x16x32_fp8_fp8(
                        la, lb0, acc[0][mt], 0, 0, 0);
                    acc[1][mt] = __builtin_amdgcn_mfma_f32_16x16x32_fp8_fp8(
                        la, lb1, acc[1][mt], 0, 0, 0);
                }
            }

            if (li < 3) {
                // ssp + fp8 pack + in-place LDS write (wave-private region; all
                // this layer's ds_reads precede these writes in program order)
#pragma unroll
                for (int mt = 0; mt < 8; ++mt) {
                    const int c = mt * 2 + (q >> 1);   // feature chunk (8 fp8)
#pragma unroll
                    for (int nt = 0; nt < 2; ++nt) {
                        float u0 = ssp_u(acc[nt][mt][0]);
                        float u1 = ssp_u(acc[nt][mt][1]);
                        float u2 = ssp_u(acc[nt][mt][2]);
                        float u3 = ssp_u(acc[nt][mt][3]);
                        int w = cvtpk2<false>(u0, u1, 0);
                        w = cvtpk2<true>(u2, u3, w);
                        const int rp = nt * 16 + l15;
                        ((u1_ma*)&act[rp * 16 + (c ^ (rp & 15))])[q & 1] = (uint_t)w;
                    }
                }
            } else {
                // head: out_e = u3 @ (ln2*oWf) + oBf, then sorted-segment reduction
                const float* hw = g_oWfF + blk * 256;
                const float ob0 = g_oBfF[blk * 2 + 0];
                const float ob1 = g_oBfF[blk * 2 + 1];
                float hs[2][2];
#pragma unroll
                for (int nt = 0; nt < 2; ++nt) {
                    float h0 = 0.f, h1 = 0.f;
#pragma unroll
                    for (int mt = 0; mt < 8; ++mt) {
#pragma unroll
                        for (int rr = 0; rr < 4; ++rr) {
                            float u = ssp_u(acc[nt][mt][rr]);
                            const int f = mt * 16 + q * 4 + rr;
                            h0 = fmaf(u, hw[f * 2 + 0], h0);
                            h1 = fmaf(u, hw[f * 2 + 1], h1);
                        }
                    }
                    h0 += __shfl_xor(h0, 16, 64);
                    h0 += __shfl_xor(h0, 32, 64);
                    h1 += __shfl_xor(h1, 16, 64);
                    h1 += __shfl_xor(h1, 32, 64);
                    hs[nt][0] = h0; hs[nt][1] = h1;
                }
                float c0v = (pp < 16) ? hs[0][0] : hs[1][0];
                float c1v = (pp < 16) ? hs[0][1] : hs[1][1];
                c0v += ob0; c1v += ob1;
                // segmented inclusive scan over the 32 sorted pairs (runs contiguous)
#pragma unroll
                for (int d = 1; d < 32; d <<= 1) {
                    float t0 = __shfl_up(c0v, d, 64);
                    float t1 = __shfl_up(c1v, d, 64);
                    int   an = __shfl_up(aseg, d, 64);
                    if (pp >= d && an == aseg) { c0v += t0; c1v += t1; }
                }
                int ain = __shfl_down(aseg, 1, 64);
                bool tail = (pp == 31) || (ain != aseg);
                if (lane < 32 && valid && tail) {
                    atomicAdd(&g_outs[(blk * NA + aseg) * 2 + 0], c0v);
                    atomicAdd(&g_outs[(blk * NA + aseg) * 2 + 1], c1v);
                }
            }
        }
    }
}

// ---------------- finalize: scale/shift + nhloss (last-block writes nh) ----------
__global__ void finalize_kernel(const int* __restrict__ Z,
                                float* __restrict__ out_atoms,   // d_out (f32)
                                float* __restrict__ out_nh)
{
    __shared__ float red[256];
    const int a = blockIdx.x * 256 + threadIdx.x;
    float s = 0.f;
    if (a < NA) {
        float v[NBLK][2];
        float t0 = 0.f, t1 = 0.f;
#pragma unroll
        for (int b = 0; b < NBLK; ++b) {
            v[b][0] = g_outs[(b * NA + a) * 2 + 0];
            v[b][1] = g_outs[(b * NA + a) * 2 + 1];
            t0 += v[b][0]; t1 += v[b][1];
        }
        const int z = Z[a];
        out_atoms[a * 2 + 0] = t0 * g_scF[z]      + g_shF[z];
        out_atoms[a * 2 + 1] = t1 * g_scF[95 + z] + g_shF[95 + z];
#pragma unroll
        for (int b = 1; b < NBLK; ++b)
#pragma unroll
            for (int o = 0; o < 2; ++o) {
                float x2 = v[b][o] * v[b][o];
                float p2 = v[b - 1][o] * v[b - 1][o];
                s += x2 / (x2 + p2 + 1e-7f);
            }
    }
    red[threadIdx.x] = s;
    __syncthreads();
    for (int st = 128; st > 0; st >>= 1) {
        if (threadIdx.x < st) red[threadIdx.x] += red[threadIdx.x + st];
        __syncthreads();
    }
    if (threadIdx.x == 0) {
        atomicAdd(&g_nh[0], red[0]);
        __threadfence();
        unsigned old = atomicAdd(&g_done, 1u);
        if (old == gridDim.x - 1) {
            float v = atomicAdd(&g_nh[0], 0.0f);   // device-scope coherent read
            out_nh[0] = v * (1.0f / 20000.0f);
        }
    }
}

// ---------------- launch ----------------
extern "C" void kernel_launch(void* const* d_in, const int* in_sizes, int n_in,
                              void* d_out, int out_size, void* d_ws, size_t ws_size,
                              hipStream_t stream)
{
    const int* Z     = (const int*)d_in[0];
    const void* R    = d_in[1];
    const int* idx_i = (const int*)d_in[2];
    const int* idx_j = (const int*)d_in[3];
    const void* iW   = d_in[4];
    const void* iB   = d_in[5];
    const void* oW   = d_in[6];
    const void* oB   = d_in[7];
    const void* oWf  = d_in[8];
    const void* oBf  = d_in[9];
    const void* scales = d_in[10];
    const void* shifts = d_in[11];

    float* out_f = (float*)d_out;   // [0,20000): outputs  [20000,270000): rij  [270000]: nhloss

    prep_kernel<<<80 + 391, 256, 0, stream>>>(iW, iB, oW, oB, R, oWf, oBf, scales, shifts);
    pairs_mlp_kernel<<<(NP + 127) / 128, 256, 0, stream>>>(idx_i, idx_j, out_f + 2 * NA);
    finalize_kernel<<<(NA + 255) / 256, 256, 0, stream>>>(Z, out_f, out_f + 2 * NA + NP);
}